// Round 3
// baseline (2191.799 us; speedup 1.0000x reference)
//
#include <hip/hip_runtime.h>

#define SS 4
#define NH 6
#define HD 32
#define NWIN 2048

typedef unsigned short u16;
typedef __attribute__((ext_vector_type(8))) short bf8;
typedef __attribute__((ext_vector_type(4))) float f4;

__device__ __forceinline__ u16 f2bf(float f) {
  unsigned int x = __builtin_bit_cast(unsigned int, f);
  unsigned int r = x + 0x7fffu + ((x >> 16) & 1u);
  return (u16)(r >> 16);
}

// K1: roll + window partition + QKV + 6-head attention + proj + reverse+roll+residual
// One block (256 thr) per window. Zero workspace: writes x1 into d_out (float32).
__global__ __launch_bounds__(256) void k_win(
    const float* __restrict__ x, const float* __restrict__ qkv_w,
    const float* __restrict__ qkv_b, const float* __restrict__ rpb,
    const float* __restrict__ proj_w, const float* __restrict__ proj_b,
    float* __restrict__ out)
{
  __shared__ short Xs[64][192];   // window input (bf16); reused as attention output O
  __shared__ short Qs[64][192];   // pre-scaled Q, cols = h*32+d
  __shared__ short Ks[64][192];
  __shared__ short Vt[192][64];   // V transposed: Vt[h*32+d][token]
  __shared__ short Wt[64][192];   // weight slab, transposed [n_local][k]
  __shared__ float Sc[64][64];
  __shared__ short Ps[64][64];

  const int w = blockIdx.x;
  const int b = w >> 6, wh = (w >> 3) & 7, wwi = w & 7;
  const int tid = threadIdx.x;
  const int wave = tid >> 6, lane = tid & 63, quad = lane >> 4, lr = lane & 15;
  const int m = wave * 16 + lr;

  // ---- Phase A: load rolled window (roll by -SS => read at +SS), f32 -> bf16 ----
  for (int it = tid; it < 3072; it += 256) {
    int row = it / 48, c4 = (it % 48) << 2;
    int i = row >> 3, j = row & 7;
    int hs = (wh * 8 + i + SS) & 63;
    int ws2 = (wwi * 8 + j + SS) & 63;
    float4 d = *(const float4*)(x + ((size_t)b * 4096 + hs * 64 + ws2) * 192 + c4);
    Xs[row][c4 + 0] = (short)f2bf(d.x);
    Xs[row][c4 + 1] = (short)f2bf(d.y);
    Xs[row][c4 + 2] = (short)f2bf(d.z);
    Xs[row][c4 + 3] = (short)f2bf(d.w);
  }

  // ---- Phase B: QKV GEMM, 9 slabs of 64 cols ----
  const float scale = 0.17677669529663687f;  // 32^-0.5
  for (int slab = 0; slab < 9; ++slab) {
    __syncthreads();
    for (int it = tid; it < 3072; it += 256) {
      int k = it >> 4, n0 = (it & 15) << 2;
      float4 d = *(const float4*)(qkv_w + (size_t)k * 576 + slab * 64 + n0);
      Wt[n0 + 0][k] = (short)f2bf(d.x);
      Wt[n0 + 1][k] = (short)f2bf(d.y);
      Wt[n0 + 2][k] = (short)f2bf(d.z);
      Wt[n0 + 3][k] = (short)f2bf(d.w);
    }
    __syncthreads();

    f4 acc[4];
#pragma unroll
    for (int i = 0; i < 4; ++i) acc[i] = (f4){0.f, 0.f, 0.f, 0.f};
#pragma unroll
    for (int kk = 0; kk < 192; kk += 32) {
      bf8 a = *(const bf8*)&Xs[m][kk + quad * 8];
#pragma unroll
      for (int nt = 0; nt < 4; ++nt) {
        bf8 bb = *(const bf8*)&Wt[nt * 16 + lr][kk + quad * 8];
        acc[nt] = __builtin_amdgcn_mfma_f32_16x16x32_bf16(a, bb, acc[nt], 0, 0, 0);
      }
    }
#pragma unroll
    for (int nt = 0; nt < 4; ++nt) {
      int c = slab * 64 + nt * 16 + lr;   // 0..575
      int part = c / 192, cc = c % 192;
      float bias = qkv_b[c];
#pragma unroll
      for (int r = 0; r < 4; ++r) {
        int row = wave * 16 + quad * 4 + r;
        float v = acc[nt][r] + bias;
        if (part == 0)      Qs[row][cc] = (short)f2bf(v * scale);
        else if (part == 1) Ks[row][cc] = (short)f2bf(v);
        else                Vt[cc][row] = (short)f2bf(v);
      }
    }
  }

  // ---- Phase C: attention, heads sequentially ----
  for (int h = 0; h < NH; ++h) {
    __syncthreads();
    {
      bf8 a = *(const bf8*)&Qs[m][h * 32 + quad * 8];
#pragma unroll
      for (int nt = 0; nt < 4; ++nt) {
        bf8 bb = *(const bf8*)&Ks[nt * 16 + lr][h * 32 + quad * 8];
        f4 s = (f4){0.f, 0.f, 0.f, 0.f};
        s = __builtin_amdgcn_mfma_f32_16x16x32_bf16(a, bb, s, 0, 0, 0);
#pragma unroll
        for (int r = 0; r < 4; ++r) {
          int row = wave * 16 + quad * 4 + r;  // query token
          int col = nt * 16 + lr;              // key token
          int dh = (row >> 3) - (col >> 3) + 7;
          int dw = (row & 7) - (col & 7) + 7;
          float bias = rpb[(dh * 15 + dw) * NH + h];
          int ph_r = wh * 8 + (row >> 3), pw_r = wwi * 8 + (row & 7);
          int ph_c = wh * 8 + (col >> 3), pw_c = wwi * 8 + (col & 7);
          int lab_r = (ph_r < 56 ? 0 : (ph_r < 60 ? 1 : 2)) * 3 +
                      (pw_r < 56 ? 0 : (pw_r < 60 ? 1 : 2));
          int lab_c = (ph_c < 56 ? 0 : (ph_c < 60 ? 1 : 2)) * 3 +
                      (pw_c < 56 ? 0 : (pw_c < 60 ? 1 : 2));
          float mask = (lab_r != lab_c) ? -100.f : 0.f;
          Sc[row][col] = s[r] + bias + mask;
        }
      }
    }
    __syncthreads();
    if (tid < 64) {
      float mx = -1e30f;
      for (int j = 0; j < 64; ++j) mx = fmaxf(mx, Sc[tid][j]);
      float sum = 0.f;
      for (int j = 0; j < 64; ++j) sum += __expf(Sc[tid][j] - mx);
      float inv = 1.f / sum;
      for (int j = 0; j < 64; ++j)
        Ps[tid][j] = (short)f2bf(__expf(Sc[tid][j] - mx) * inv);
    }
    __syncthreads();
    f4 o[2];
#pragma unroll
    for (int i = 0; i < 2; ++i) o[i] = (f4){0.f, 0.f, 0.f, 0.f};
#pragma unroll
    for (int kk = 0; kk < 64; kk += 32) {
      bf8 a = *(const bf8*)&Ps[m][kk + quad * 8];
#pragma unroll
      for (int nt = 0; nt < 2; ++nt) {
        bf8 bb = *(const bf8*)&Vt[h * 32 + nt * 16 + lr][kk + quad * 8];
        o[nt] = __builtin_amdgcn_mfma_f32_16x16x32_bf16(a, bb, o[nt], 0, 0, 0);
      }
    }
#pragma unroll
    for (int nt = 0; nt < 2; ++nt)
#pragma unroll
      for (int r = 0; r < 4; ++r)
        Xs[wave * 16 + quad * 4 + r][h * 32 + nt * 16 + lr] = (short)f2bf(o[nt][r]);
  }

  // ---- Phase D: proj + reverse + roll-back + residual -> out (f32) ----
  for (int s3 = 0; s3 < 3; ++s3) {
    __syncthreads();
    for (int it = tid; it < 3072; it += 256) {
      int k = it >> 4, n0 = (it & 15) << 2;
      float4 d = *(const float4*)(proj_w + (size_t)k * 192 + s3 * 64 + n0);
      Wt[n0 + 0][k] = (short)f2bf(d.x);
      Wt[n0 + 1][k] = (short)f2bf(d.y);
      Wt[n0 + 2][k] = (short)f2bf(d.z);
      Wt[n0 + 3][k] = (short)f2bf(d.w);
    }
    __syncthreads();
    f4 acc[4];
#pragma unroll
    for (int i = 0; i < 4; ++i) acc[i] = (f4){0.f, 0.f, 0.f, 0.f};
#pragma unroll
    for (int kk = 0; kk < 192; kk += 32) {
      bf8 a = *(const bf8*)&Xs[m][kk + quad * 8];  // Xs now holds O
#pragma unroll
      for (int nt = 0; nt < 4; ++nt) {
        bf8 bb = *(const bf8*)&Wt[nt * 16 + lr][kk + quad * 8];
        acc[nt] = __builtin_amdgcn_mfma_f32_16x16x32_bf16(a, bb, acc[nt], 0, 0, 0);
      }
    }
#pragma unroll
    for (int nt = 0; nt < 4; ++nt) {
      int c = s3 * 64 + nt * 16 + lr;
      float bias = proj_b[c];
#pragma unroll
      for (int r = 0; r < 4; ++r) {
        int row = wave * 16 + quad * 4 + r;
        int i = row >> 3, j = row & 7;
        int ho = (wh * 8 + i + SS) & 63;
        int wo = (wwi * 8 + j + SS) & 63;
        size_t off = ((size_t)b * 4096 + ho * 64 + wo) * 192 + c;
        out[off] = acc[nt][r] + bias + x[off];
      }
    }
  }
}

// K2: fused FC1 + GELU + FC2 + residual, IN-PLACE on out (block-private rows)
__global__ __launch_bounds__(256) void k_mlp(
    const float* __restrict__ fc1_w, const float* __restrict__ fc1_b,
    const float* __restrict__ fc2_w, const float* __restrict__ fc2_b,
    float* __restrict__ out)
{
  const int blk = blockIdx.x;
  const int tid = threadIdx.x;
  const int wave = tid >> 6, lane = tid & 63, quad = lane >> 4, lr = lane & 15;

  __shared__ short Xs[64][192];
  __shared__ short Hs[64][768];
  __shared__ short Wl[12288];

  const size_t r0 = (size_t)blk * 64;
  for (int it = tid; it < 3072; it += 256) {
    int row = it / 48, c4 = (it % 48) << 2;
    float4 d = *(const float4*)(out + (r0 + row) * 192 + c4);
    Xs[row][c4 + 0] = (short)f2bf(d.x);
    Xs[row][c4 + 1] = (short)f2bf(d.y);
    Xs[row][c4 + 2] = (short)f2bf(d.z);
    Xs[row][c4 + 3] = (short)f2bf(d.w);
  }
  const int m = wave * 16 + lr;

  // FC1 + GELU -> Hs
  for (int s = 0; s < 12; ++s) {
    __syncthreads();
    for (int it = tid; it < 3072; it += 256) {
      int k = it >> 4, n0 = (it & 15) << 2;
      float4 d = *(const float4*)(fc1_w + (size_t)k * 768 + s * 64 + n0);
      Wl[(n0 + 0) * 192 + k] = (short)f2bf(d.x);
      Wl[(n0 + 1) * 192 + k] = (short)f2bf(d.y);
      Wl[(n0 + 2) * 192 + k] = (short)f2bf(d.z);
      Wl[(n0 + 3) * 192 + k] = (short)f2bf(d.w);
    }
    __syncthreads();
    f4 acc[4];
#pragma unroll
    for (int i = 0; i < 4; ++i) acc[i] = (f4){0.f, 0.f, 0.f, 0.f};
#pragma unroll
    for (int kk = 0; kk < 192; kk += 32) {
      bf8 a = *(const bf8*)&Xs[m][kk + quad * 8];
#pragma unroll
      for (int nt = 0; nt < 4; ++nt) {
        bf8 bb = *(const bf8*)&Wl[(nt * 16 + lr) * 192 + kk + quad * 8];
        acc[nt] = __builtin_amdgcn_mfma_f32_16x16x32_bf16(a, bb, acc[nt], 0, 0, 0);
      }
    }
#pragma unroll
    for (int nt = 0; nt < 4; ++nt) {
      int c = s * 64 + nt * 16 + lr;
      float bias = fc1_b[c];
#pragma unroll
      for (int r = 0; r < 4; ++r) {
        int row = wave * 16 + quad * 4 + r;
        float v = acc[nt][r] + bias;
        float g = 0.5f * v * (1.f + erff(v * 0.70710678118654752f));
        Hs[row][c] = (short)f2bf(g);
      }
    }
  }

  // FC2 + residual (residual re-read from global in f32 for accuracy)
  f4 acc2[12];
#pragma unroll
  for (int i = 0; i < 12; ++i) acc2[i] = (f4){0.f, 0.f, 0.f, 0.f};
  for (int s = 0; s < 12; ++s) {
    __syncthreads();
    for (int it = tid; it < 3072; it += 256) {
      int kl = it / 48, n0 = (it % 48) << 2;
      float4 d = *(const float4*)(fc2_w + (size_t)(s * 64 + kl) * 192 + n0);
      Wl[(n0 + 0) * 64 + kl] = (short)f2bf(d.x);
      Wl[(n0 + 1) * 64 + kl] = (short)f2bf(d.y);
      Wl[(n0 + 2) * 64 + kl] = (short)f2bf(d.z);
      Wl[(n0 + 3) * 64 + kl] = (short)f2bf(d.w);
    }
    __syncthreads();
#pragma unroll
    for (int kk = 0; kk < 64; kk += 32) {
      bf8 a = *(const bf8*)&Hs[m][s * 64 + kk + quad * 8];
#pragma unroll
      for (int nt = 0; nt < 12; ++nt) {
        bf8 bb = *(const bf8*)&Wl[(nt * 16 + lr) * 64 + kk + quad * 8];
        acc2[nt] = __builtin_amdgcn_mfma_f32_16x16x32_bf16(a, bb, acc2[nt], 0, 0, 0);
      }
    }
  }
  __syncthreads();
#pragma unroll
  for (int nt = 0; nt < 12; ++nt) {
    int c = nt * 16 + lr;
    float bias = fc2_b[c];
#pragma unroll
    for (int r = 0; r < 4; ++r) {
      int row = wave * 16 + quad * 4 + r;
      size_t off = (r0 + row) * 192 + c;
      out[off] = acc2[nt][r] + bias + out[off];
    }
  }
}

extern "C" void kernel_launch(void* const* d_in, const int* in_sizes, int n_in,
                              void* d_out, int out_size, void* d_ws, size_t ws_size,
                              hipStream_t stream)
{
  const float* x      = (const float*)d_in[0];
  const float* rpb    = (const float*)d_in[1];
  const float* qkv_w  = (const float*)d_in[2];
  const float* qkv_b  = (const float*)d_in[3];
  const float* proj_w = (const float*)d_in[4];
  const float* proj_b = (const float*)d_in[5];
  const float* fc1_w  = (const float*)d_in[6];
  const float* fc1_b  = (const float*)d_in[7];
  const float* fc2_w  = (const float*)d_in[8];
  const float* fc2_b  = (const float*)d_in[9];
  float* out = (float*)d_out;

  k_win<<<dim3(NWIN), 256, 0, stream>>>(x, qkv_w, qkv_b, rpb, proj_w, proj_b, out);
  k_mlp<<<dim3(NWIN), 256, 0, stream>>>(fc1_w, fc1_b, fc2_w, fc2_b, out);
}

// Round 4
// 900.810 us; speedup vs baseline: 2.4331x; 2.4331x over previous
//
#include <hip/hip_runtime.h>

#define SS 4
#define NH 6
#define HD 32
#define NWIN 2048
#define P192 200   // padded row stride for k=192 rows (400 B -> bank +4)
#define P64  72    // padded row stride for k=64 rows  (144 B -> bank +4)

typedef unsigned short u16;
typedef __attribute__((ext_vector_type(8))) short bf8;
typedef __attribute__((ext_vector_type(4))) float f4;

__device__ __forceinline__ u16 f2bf(float f) {
  unsigned int x = __builtin_bit_cast(unsigned int, f);
  unsigned int r = x + 0x7fffu + ((x >> 16) & 1u);
  return (u16)(r >> 16);
}

// ---- prep: f32 [K][N] -> bf16 transposed [N][K], optional scale for n<scale_n ----
__global__ __launch_bounds__(256) void k_prep(
    const float* __restrict__ src, u16* __restrict__ dst,
    int K, int N, int scale_n, float scale)
{
  int idx = blockIdx.x * 256 + threadIdx.x;
  int total = (K >> 2) * N;
  if (idx >= total) return;
  int n = idx % N;
  int kq = (idx / N) << 2;
  float s = (n < scale_n) ? scale : 1.f;
  ushort4 o;
  o.x = f2bf(src[(size_t)(kq + 0) * N + n] * s);
  o.y = f2bf(src[(size_t)(kq + 1) * N + n] * s);
  o.z = f2bf(src[(size_t)(kq + 2) * N + n] * s);
  o.w = f2bf(src[(size_t)(kq + 3) * N + n] * s);
  *(ushort4*)(dst + (size_t)n * K + kq) = o;
}

// ---- K1: roll+partition+QKV+attention(6 heads)+proj+reverse+roll+residual ----
__global__ __launch_bounds__(256) void k_win(
    const float* __restrict__ x, const u16* __restrict__ qkvT,
    const float* __restrict__ qkv_b, const float* __restrict__ rpb,
    const u16* __restrict__ projT, const float* __restrict__ proj_b,
    float* __restrict__ out)
{
  __shared__ short Os[64][P192];   // attention output O (proj A-tile)
  __shared__ short Qs[64][P192];   // pre-scaled Q (cols = h*32+d)
  __shared__ short Ks[64][P192];
  __shared__ short Vt[192][P64];   // V transposed: Vt[h*32+d][token]
  __shared__ short Wt[64][P192];   // weight slab [n_local][k]
  __shared__ float Sc[64][65];
  __shared__ short Ps[64][P64];

  const int w = blockIdx.x;
  const int b = w >> 6, wh = (w >> 3) & 7, wwi = w & 7;
  const int tid = threadIdx.x;
  const int wave = tid >> 6, lane = tid & 63, quad = lane >> 4, lr = lane & 15;
  const int m = wave * 16 + lr;

  // Phase A: A-fragments of rolled window straight into registers
  bf8 af[6];
  {
    int token = wave * 16 + lr;
    int hs = (wh * 8 + (token >> 3) + SS) & 63;
    int ws2 = (wwi * 8 + (token & 7) + SS) & 63;
    const float* base = x + ((size_t)b * 4096 + hs * 64 + ws2) * 192 + quad * 8;
#pragma unroll
    for (int kc = 0; kc < 6; ++kc) {
      float4 lo = *(const float4*)(base + kc * 32);
      float4 hi = *(const float4*)(base + kc * 32 + 4);
      bf8 v;
      v[0] = (short)f2bf(lo.x); v[1] = (short)f2bf(lo.y);
      v[2] = (short)f2bf(lo.z); v[3] = (short)f2bf(lo.w);
      v[4] = (short)f2bf(hi.x); v[5] = (short)f2bf(hi.y);
      v[6] = (short)f2bf(hi.z); v[7] = (short)f2bf(hi.w);
      af[kc] = v;
    }
  }

  // Phase B: QKV GEMM, 9 slabs of 64 cols (weights pre-transposed bf16)
  const float scale = 0.17677669529663687f;
  for (int slab = 0; slab < 9; ++slab) {
    __syncthreads();
    for (int it = tid; it < 1536; it += 256) {
      int nl = it / 24, kq = (it % 24) << 3;
      *(uint4*)&Wt[nl][kq] = *(const uint4*)(qkvT + (size_t)(slab * 64 + nl) * 192 + kq);
    }
    __syncthreads();
    f4 acc[4];
#pragma unroll
    for (int i = 0; i < 4; ++i) acc[i] = (f4){0.f, 0.f, 0.f, 0.f};
#pragma unroll
    for (int kc = 0; kc < 6; ++kc) {
#pragma unroll
      for (int nt = 0; nt < 4; ++nt) {
        bf8 bb = *(const bf8*)&Wt[nt * 16 + lr][kc * 32 + quad * 8];
        acc[nt] = __builtin_amdgcn_mfma_f32_16x16x32_bf16(af[kc], bb, acc[nt], 0, 0, 0);
      }
    }
#pragma unroll
    for (int nt = 0; nt < 4; ++nt) {
      int c = slab * 64 + nt * 16 + lr;   // 0..575
      int part = c / 192, cc = c % 192;
      float bias = qkv_b[c];
      if (part == 0) bias *= scale;       // weights pre-scaled; scale bias too
#pragma unroll
      for (int r = 0; r < 4; ++r) {
        int row = wave * 16 + quad * 4 + r;
        float v = acc[nt][r] + bias;
        if (part == 0)      Qs[row][cc] = (short)f2bf(v);
        else if (part == 1) Ks[row][cc] = (short)f2bf(v);
        else                Vt[cc][row] = (short)f2bf(v);
      }
    }
  }

  // Phase C: attention per head
  for (int h = 0; h < NH; ++h) {
    __syncthreads();
    {
      bf8 a = *(const bf8*)&Qs[m][h * 32 + quad * 8];
#pragma unroll
      for (int nt = 0; nt < 4; ++nt) {
        bf8 bb = *(const bf8*)&Ks[nt * 16 + lr][h * 32 + quad * 8];
        f4 s = (f4){0.f, 0.f, 0.f, 0.f};
        s = __builtin_amdgcn_mfma_f32_16x16x32_bf16(a, bb, s, 0, 0, 0);
#pragma unroll
        for (int r = 0; r < 4; ++r) {
          int row = wave * 16 + quad * 4 + r;  // query token
          int col = nt * 16 + lr;              // key token
          int dh = (row >> 3) - (col >> 3) + 7;
          int dw = (row & 7) - (col & 7) + 7;
          float bias = rpb[(dh * 15 + dw) * NH + h];
          int ph_r = wh * 8 + (row >> 3), pw_r = wwi * 8 + (row & 7);
          int ph_c = wh * 8 + (col >> 3), pw_c = wwi * 8 + (col & 7);
          int lab_r = (ph_r < 56 ? 0 : (ph_r < 60 ? 1 : 2)) * 3 +
                      (pw_r < 56 ? 0 : (pw_r < 60 ? 1 : 2));
          int lab_c = (ph_c < 56 ? 0 : (ph_c < 60 ? 1 : 2)) * 3 +
                      (pw_c < 56 ? 0 : (pw_c < 60 ? 1 : 2));
          float mask = (lab_r != lab_c) ? -100.f : 0.f;
          Sc[row][col] = s[r] + bias + mask;
        }
      }
    }
    __syncthreads();
    {  // softmax: 4 threads per row, shuffle reductions
      int row = tid >> 2, q = tid & 3;
      float ex[16], mx = -1e30f;
#pragma unroll
      for (int j = 0; j < 16; ++j) { ex[j] = Sc[row][q * 16 + j]; mx = fmaxf(mx, ex[j]); }
      mx = fmaxf(mx, __shfl_xor(mx, 1));
      mx = fmaxf(mx, __shfl_xor(mx, 2));
      float sum = 0.f;
#pragma unroll
      for (int j = 0; j < 16; ++j) { ex[j] = __expf(ex[j] - mx); sum += ex[j]; }
      sum += __shfl_xor(sum, 1);
      sum += __shfl_xor(sum, 2);
      float inv = 1.f / sum;
#pragma unroll
      for (int jj = 0; jj < 8; ++jj) {
        unsigned int pk = (unsigned int)f2bf(ex[2 * jj] * inv) |
                          ((unsigned int)f2bf(ex[2 * jj + 1] * inv) << 16);
        *(unsigned int*)&Ps[row][q * 16 + 2 * jj] = pk;
      }
    }
    __syncthreads();
    f4 o[2];
#pragma unroll
    for (int i = 0; i < 2; ++i) o[i] = (f4){0.f, 0.f, 0.f, 0.f};
#pragma unroll
    for (int kc = 0; kc < 2; ++kc) {
      bf8 a = *(const bf8*)&Ps[m][kc * 32 + quad * 8];
#pragma unroll
      for (int nt = 0; nt < 2; ++nt) {
        bf8 bb = *(const bf8*)&Vt[h * 32 + nt * 16 + lr][kc * 32 + quad * 8];
        o[nt] = __builtin_amdgcn_mfma_f32_16x16x32_bf16(a, bb, o[nt], 0, 0, 0);
      }
    }
#pragma unroll
    for (int nt = 0; nt < 2; ++nt)
#pragma unroll
      for (int r = 0; r < 4; ++r)
        Os[wave * 16 + quad * 4 + r][h * 32 + nt * 16 + lr] = (short)f2bf(o[nt][r]);
  }

  // Phase D: proj + reverse + roll-back + residual -> out (f32)
  for (int s3 = 0; s3 < 3; ++s3) {
    __syncthreads();
    for (int it = tid; it < 1536; it += 256) {
      int nl = it / 24, kq = (it % 24) << 3;
      *(uint4*)&Wt[nl][kq] = *(const uint4*)(projT + (size_t)(s3 * 64 + nl) * 192 + kq);
    }
    __syncthreads();
    f4 acc[4];
#pragma unroll
    for (int i = 0; i < 4; ++i) acc[i] = (f4){0.f, 0.f, 0.f, 0.f};
#pragma unroll
    for (int kc = 0; kc < 6; ++kc) {
      bf8 a = *(const bf8*)&Os[m][kc * 32 + quad * 8];
#pragma unroll
      for (int nt = 0; nt < 4; ++nt) {
        bf8 bb = *(const bf8*)&Wt[nt * 16 + lr][kc * 32 + quad * 8];
        acc[nt] = __builtin_amdgcn_mfma_f32_16x16x32_bf16(a, bb, acc[nt], 0, 0, 0);
      }
    }
#pragma unroll
    for (int nt = 0; nt < 4; ++nt) {
      int c = s3 * 64 + nt * 16 + lr;
      float bias = proj_b[c];
#pragma unroll
      for (int r = 0; r < 4; ++r) {
        int row = wave * 16 + quad * 4 + r;
        int ho = (wh * 8 + (row >> 3) + SS) & 63;
        int wo = (wwi * 8 + (row & 7) + SS) & 63;
        size_t off = ((size_t)b * 4096 + ho * 64 + wo) * 192 + c;
        out[off] = acc[nt][r] + bias + x[off];
      }
    }
  }
}

// ---- K2: fused FC1+GELU+FC2+residual, slab-streamed (61 KB LDS, 2 blk/CU) ----
__global__ __launch_bounds__(256, 2) void k_mlp(
    const u16* __restrict__ fc1T, const float* __restrict__ fc1_b,
    const u16* __restrict__ fc2T, const float* __restrict__ fc2_b,
    float* __restrict__ out)
{
  __shared__ short Wl1[64][P192];   // fc1 slab [n_local][k=192]
  __shared__ short Wl2[192][P64];   // fc2 slab [n=192][k_local=64]
  __shared__ short Hslab[64][P64];  // H slab (C-layout write, A-layout read)

  const int blk = blockIdx.x;
  const int tid = threadIdx.x;
  const int wave = tid >> 6, lane = tid & 63, quad = lane >> 4, lr = lane & 15;
  const int m = wave * 16 + lr;
  const size_t r0 = (size_t)blk * 64;

  // A-fragments of x1 straight from global (f32 -> bf16 regs)
  bf8 af[6];
  {
    const float* base = out + (r0 + wave * 16 + lr) * 192 + quad * 8;
#pragma unroll
    for (int kc = 0; kc < 6; ++kc) {
      float4 lo = *(const float4*)(base + kc * 32);
      float4 hi = *(const float4*)(base + kc * 32 + 4);
      bf8 v;
      v[0] = (short)f2bf(lo.x); v[1] = (short)f2bf(lo.y);
      v[2] = (short)f2bf(lo.z); v[3] = (short)f2bf(lo.w);
      v[4] = (short)f2bf(hi.x); v[5] = (short)f2bf(hi.y);
      v[6] = (short)f2bf(hi.z); v[7] = (short)f2bf(hi.w);
      af[kc] = v;
    }
  }

  f4 acc2[12];
#pragma unroll
  for (int i = 0; i < 12; ++i) acc2[i] = (f4){0.f, 0.f, 0.f, 0.f};

  for (int s = 0; s < 12; ++s) {
    __syncthreads();  // protect Wl1/Wl2/Hslab from previous iteration's readers
    // stage fc1 slab (64 n-rows x 192 k) and fc2 slab (192 n-rows x 64 k)
    for (int it = tid; it < 1536; it += 256) {
      int nl = it / 24, kq = (it % 24) << 3;
      *(uint4*)&Wl1[nl][kq] = *(const uint4*)(fc1T + (size_t)(s * 64 + nl) * 192 + kq);
    }
    for (int it = tid; it < 1536; it += 256) {
      int nl = it >> 3, kq = (it & 7) << 3;
      *(uint4*)&Wl2[nl][kq] = *(const uint4*)(fc2T + (size_t)nl * 768 + s * 64 + kq);
    }
    __syncthreads();
    // FC1 -> H slab (64 cols), + bias + GELU
    f4 hacc[4];
#pragma unroll
    for (int i = 0; i < 4; ++i) hacc[i] = (f4){0.f, 0.f, 0.f, 0.f};
#pragma unroll
    for (int kc = 0; kc < 6; ++kc) {
#pragma unroll
      for (int nt = 0; nt < 4; ++nt) {
        bf8 bb = *(const bf8*)&Wl1[nt * 16 + lr][kc * 32 + quad * 8];
        hacc[nt] = __builtin_amdgcn_mfma_f32_16x16x32_bf16(af[kc], bb, hacc[nt], 0, 0, 0);
      }
    }
#pragma unroll
    for (int nt = 0; nt < 4; ++nt) {
      float bias = fc1_b[s * 64 + nt * 16 + lr];
#pragma unroll
      for (int r = 0; r < 4; ++r) {
        float v = hacc[nt][r] + bias;
        float g = 0.5f * v * (1.f + erff(v * 0.70710678118654752f));
        Hslab[wave * 16 + quad * 4 + r][nt * 16 + lr] = (short)f2bf(g);
      }
    }
    __syncthreads();
    // FC2 partial accumulation over this 64-wide K slab
#pragma unroll
    for (int kc = 0; kc < 2; ++kc) {
      bf8 a = *(const bf8*)&Hslab[m][kc * 32 + quad * 8];
#pragma unroll
      for (int nt = 0; nt < 12; ++nt) {
        bf8 bb = *(const bf8*)&Wl2[nt * 16 + lr][kc * 32 + quad * 8];
        acc2[nt] = __builtin_amdgcn_mfma_f32_16x16x32_bf16(a, bb, acc2[nt], 0, 0, 0);
      }
    }
  }

  // epilogue: + bias + residual (f32 re-read), in-place
#pragma unroll
  for (int nt = 0; nt < 12; ++nt) {
    int c = nt * 16 + lr;
    float bias = fc2_b[c];
#pragma unroll
    for (int r = 0; r < 4; ++r) {
      int row = wave * 16 + quad * 4 + r;
      size_t off = (r0 + row) * 192 + c;
      out[off] = acc2[nt][r] + bias + out[off];
    }
  }
}

extern "C" void kernel_launch(void* const* d_in, const int* in_sizes, int n_in,
                              void* d_out, int out_size, void* d_ws, size_t ws_size,
                              hipStream_t stream)
{
  const float* x      = (const float*)d_in[0];
  const float* rpb    = (const float*)d_in[1];
  const float* qkv_w  = (const float*)d_in[2];
  const float* qkv_b  = (const float*)d_in[3];
  const float* proj_w = (const float*)d_in[4];
  const float* proj_b = (const float*)d_in[5];
  const float* fc1_w  = (const float*)d_in[6];
  const float* fc1_b  = (const float*)d_in[7];
  const float* fc2_w  = (const float*)d_in[8];
  const float* fc2_b  = (const float*)d_in[9];
  float* out = (float*)d_out;

  // bf16 transposed weights in workspace (885 KB total)
  u16* qkvT = (u16*)d_ws;                 // [576][192]
  u16* projT = qkvT + 576 * 192;          // [192][192]
  u16* fc1T  = projT + 192 * 192;         // [768][192]
  u16* fc2T  = fc1T + 768 * 192;          // [192][768]

  const float scale = 0.17677669529663687f;  // 32^-0.5 baked into W_q
  k_prep<<<108, 256, 0, stream>>>(qkv_w, qkvT, 192, 576, 192, scale);
  k_prep<<< 36, 256, 0, stream>>>(proj_w, projT, 192, 192, 0, 1.f);
  k_prep<<<144, 256, 0, stream>>>(fc1_w, fc1T, 192, 768, 0, 1.f);
  k_prep<<<144, 256, 0, stream>>>(fc2_w, fc2T, 768, 192, 0, 1.f);

  k_win<<<dim3(NWIN), 256, 0, stream>>>(x, qkvT, qkv_b, rpb, projT, proj_b, out);
  k_mlp<<<dim3(NWIN), 256, 0, stream>>>(fc1T, fc1_b, fc2T, fc2_b, out);
}